// Round 13
// baseline (385.798 us; speedup 1.0000x reference)
//
#include <hip/hip_runtime.h>
#include <hip/hip_fp16.h>
#include <stdint.h>

#define IN_F   4096
#define OUT_F  11008
#define TOKENS 2048
#define BM 128
#define BN 128
#define BK 64
#define NT (IN_F / BK)     // 64 K-tiles
#define NGROUP 32
#define OPW (OUT_F / 8)

typedef _Float16 f16;
typedef __attribute__((ext_vector_type(2))) _Float16 f16x2;
typedef __attribute__((ext_vector_type(8))) _Float16 f16x8;
typedef __attribute__((ext_vector_type(4))) float f32x4;

// dequant one packed word -> 8 f16 in pair-permuted k-order (j, j+4)
static __device__ __forceinline__ f16x8 dequant8(uint32_t w, f16x2 sv, f16x2 zv) {
    uint32_t p0 = (w & 0x000F000Fu) | 0x64006400u;           // 1024 + nibble (exact f16)
    uint32_t p1 = ((w >> 4)  & 0x000F000Fu) | 0x64006400u;
    uint32_t p2 = ((w >> 8)  & 0x000F000Fu) | 0x64006400u;
    uint32_t p3 = ((w >> 12) & 0x000F000Fu) | 0x64006400u;
    f16x2 h0 = (__builtin_bit_cast(f16x2, p0) + zv) * sv;    // exact (w - z - 1), then * s
    f16x2 h1 = (__builtin_bit_cast(f16x2, p1) + zv) * sv;
    f16x2 h2 = (__builtin_bit_cast(f16x2, p2) + zv) * sv;
    f16x2 h3 = (__builtin_bit_cast(f16x2, p3) + zv) * sv;
    f16x8 o;
    o[0] = h0[0]; o[1] = h0[1];
    o[2] = h1[0]; o[3] = h1[1];
    o[4] = h2[0]; o[5] = h2[1];
    o[6] = h3[0]; o[7] = h3[1];
    return o;
}

// pre-pass: x f32 -> f16 with intra-octet pair permutation (0,4,1,5,2,6,3,7)
__global__ __launch_bounds__(256) void cvt_perm_kernel(const float* __restrict__ x,
                                                       f16* __restrict__ xws) {
    const int o = blockIdx.x * 256 + threadIdx.x;   // octet id
    const float4 a = *reinterpret_cast<const float4*>(x + (size_t)o * 8);
    const float4 b = *reinterpret_cast<const float4*>(x + (size_t)o * 8 + 4);
    f16x8 v;
    v[0] = (f16)a.x; v[1] = (f16)b.x; v[2] = (f16)a.y; v[3] = (f16)b.y;
    v[4] = (f16)a.z; v[5] = (f16)b.z; v[6] = (f16)a.w; v[7] = (f16)b.w;
    *reinterpret_cast<f16x8*>(xws + (size_t)o * 8) = v;
}

template<bool USE_WS>
__global__ __launch_bounds__(512, 4) void qgemm_kernel(
    const float*    __restrict__ x,
    const f16*      __restrict__ xws,
    const uint32_t* __restrict__ qweight,
    const uint32_t* __restrict__ qzeros,
    const int*      __restrict__ qscales,
    const float*    __restrict__ qscales_zeros,
    const float*    __restrict__ qscales_scales,
    float*          __restrict__ out)
{
    // B only in LDS: [128 cols][64 k] f16, chunk (col, slot) holds k-octet
    // slot ^ (col&7) — conflict-free b128 phases. A fragments come straight
    // from L2 (xws is per-XCD L2-resident). Epilogue reuses Bsh as scratch.
    __shared__ __align__(16) f16 Bsh[2][BN * BK];    // 2 x 16 KiB = 32 KiB

    const int tid  = threadIdx.x;
    const int lane = tid & 63;
    const int wid  = tid >> 6;      // 0..7
    const int kg   = wid >> 2;      // k-octet group (0: oct 0-3, 1: oct 4-7)
    const int wm   = (wid >> 1) & 1;
    const int wn   = wid & 1;

    // XCD map: bid&7 = XCD; mt = bid&15 -> XCD x hosts A-panels {x, x+8} in its L2
    const int mt = blockIdx.x & 15;
    const int nt = blockIdx.x >> 4;
    const int m0 = mt * BM;
    const int n0 = nt * BN;

    // ---------- B side: thread owns 1 column, 2 consecutive k-octet rows ----------
    const int colb = tid & 127;
    const int og2  = (tid >> 7) << 1;    // 0,2,4,6
    const int ncol = n0 + colb;
    const float ssv   = qscales_scales[ncol];
    const float qzssv = qscales_zeros[ncol] * ssv;
    int bo[2];
    #pragma unroll
    for (int r = 0; r < 2; ++r)
        bo[r] = colb * BK + ((og2 + r) ^ (colb & 7)) * 8;
    const uint32_t* bptr = qweight + (size_t)og2 * OUT_F + ncol;

    // ---------- A side: 4 fragment pointers straight into xws / x ----------
    const int lr = lane & 15;
    const int lo = lane >> 4;
    const int koct = kg * 4 + lo;            // 0..7
    const f16*   afp[4];
    const float* ffp[4];
    #pragma unroll
    for (int f = 0; f < 4; ++f) {
        const int ra = wm * 64 + f * 16 + lr;
        afp[f] = xws + (size_t)(m0 + ra) * IN_F + koct * 8;
        ffp[f] = x   + (size_t)(m0 + ra) * IN_F + koct * 8;
    }

    // ---------- B fragment read offsets ----------
    int offB[4];
    #pragma unroll
    for (int f = 0; f < 4; ++f) {
        const int rb = wn * 64 + f * 16 + lr;
        offB[f] = rb * BK + (koct ^ (rb & 7)) * 8;
    }

    f32x4 acc[4][4];
    #pragma unroll
    for (int i = 0; i < 4; ++i)
        #pragma unroll
        for (int j = 0; j < 4; ++j) {
            f32x4 z = {0.f, 0.f, 0.f, 0.f};
            acc[i][j] = z;
        }

    auto load_bw = [&](int t_, uint32_t* w) {
        const uint32_t* p = bptr + (size_t)t_ * 8 * OUT_F;
        w[0] = p[0];
        w[1] = p[OUT_F];
    };
    auto mkc = [&](f16x2& sv_, f16x2& zv_, int sw_, uint32_t zw_) {
        const float sf = (float)sw_ * ssv - qzssv;
        const int   z  = (int)((zw_ >> ((ncol & 7) * 4)) & 0xFu);
        const f16 sh = (f16)sf;
        const f16 zh = (f16)(float)(-(1025 + z));   // -(1024 + (z+1)), exact in f16
        sv_[0] = sh; sv_[1] = sh;
        zv_[0] = zh; zv_[1] = zh;
    };
    auto stage_B = [&](int buf, const uint32_t* w, f16x2 sv_, f16x2 zv_) {
        *reinterpret_cast<f16x8*>(&Bsh[buf][bo[0]]) = dequant8(w[0], sv_, zv_);
        *reinterpret_cast<f16x8*>(&Bsh[buf][bo[1]]) = dequant8(w[1], sv_, zv_);
    };
    auto compute = [&](int buf, int t_) {
        f16x8 af[4], bf[4];
        if constexpr (USE_WS) {
            #pragma unroll
            for (int f = 0; f < 4; ++f)
                af[f] = *reinterpret_cast<const f16x8*>(afp[f] + (size_t)t_ * BK);
        } else {
            #pragma unroll
            for (int f = 0; f < 4; ++f) {
                const float* p = ffp[f] + (size_t)t_ * BK;
                const float4 v0 = *reinterpret_cast<const float4*>(p);
                const float4 v1 = *reinterpret_cast<const float4*>(p + 4);
                f16x8 v;
                v[0] = (f16)v0.x; v[1] = (f16)v1.x; v[2] = (f16)v0.y; v[3] = (f16)v1.y;
                v[4] = (f16)v0.z; v[5] = (f16)v1.z; v[6] = (f16)v0.w; v[7] = (f16)v1.w;
                af[f] = v;
            }
        }
        #pragma unroll
        for (int f = 0; f < 4; ++f)
            bf[f] = *reinterpret_cast<const f16x8*>(&Bsh[buf][offB[f]]);
        __builtin_amdgcn_s_setprio(1);
        #pragma unroll
        for (int i = 0; i < 4; ++i)
            #pragma unroll
            for (int j = 0; j < 4; ++j)
                acc[i][j] = __builtin_amdgcn_mfma_f32_16x16x32_f16(
                    af[i], bf[j], acc[i][j], 0, 0, 0);
        __builtin_amdgcn_s_setprio(0);
    };

    uint32_t wcur[2], wnxt[2];
    int swN; uint32_t zwN;
    f16x2 sv, zv, svN, zvN;

    // ---------------- prologue: stage B(0); prime words(1) + group-1 scales ------
    {
        uint32_t w0i[2];
        load_bw(0, w0i);
        const int      sw0 = qscales[ncol];
        const uint32_t zw0 = qzeros[ncol >> 3];
        load_bw(1, wcur);
        swN = qscales[OUT_F + ncol];           // group 1
        zwN = qzeros[OPW + (ncol >> 3)];
        mkc(sv, zv, sw0, zw0);                 // group 0 (tiles 0,1)
        stage_B(0, w0i, sv, zv);
        asm volatile("s_waitcnt lgkmcnt(0)" ::: "memory");
        __builtin_amdgcn_s_barrier();
    }

    // ---------------- main loop: 2 tiles per iteration, 1 barrier per tile -------
    for (int t = 0; t < NT; t += 2) {
        // ---- even body: compute tile t (buf0); stage B(t+1) (buf1)
        {
            mkc(svN, zvN, swN, zwN);                   // group t/2+1 (for odd body)
            stage_B(1, wcur, sv, zv);                  // tile t+1, group t/2
            load_bw(t + 2 < NT ? t + 2 : NT - 1, wnxt);
            {
                const int g2 = (t >> 1) + 2 < NGROUP ? (t >> 1) + 2 : NGROUP - 1;
                swN = qscales[(size_t)g2 * OUT_F + ncol];
                zwN = qzeros[(size_t)g2 * OPW + (ncol >> 3)];
            }
            compute(0, t);
            asm volatile("s_waitcnt lgkmcnt(0)" ::: "memory");
            __builtin_amdgcn_s_barrier();
        }
        // ---- odd body: compute tile t+1 (buf1); stage B(t+2) (buf0)
        {
            sv = svN; zv = zvN;                        // group t/2+1
            stage_B(0, wnxt, sv, zv);                  // tile t+2
            load_bw(t + 3 < NT ? t + 3 : NT - 1, wcur);
            compute(1, t + 1);
            asm volatile("s_waitcnt lgkmcnt(0)" ::: "memory");
            __builtin_amdgcn_s_barrier();
        }
    }

    // ---------------- cross-k-group reduction (2 rounds over Bsh, 32 KiB) --------
    __syncthreads();
    f32x4* scratch = reinterpret_cast<f32x4*>(&Bsh[0][0]);   // 2048 f32x4
    const int wpos = wid & 3;
    #pragma unroll
    for (int q = 0; q < 2; ++q) {            // acc rows {0,1} then {2,3}
        if (kg == 1) {
            #pragma unroll
            for (int di = 0; di < 2; ++di)
                #pragma unroll
                for (int j = 0; j < 4; ++j)
                    scratch[wpos * 512 + (di * 4 + j) * 64 + lane] = acc[2 * q + di][j];
        }
        __syncthreads();
        if (kg == 0) {
            #pragma unroll
            for (int di = 0; di < 2; ++di)
                #pragma unroll
                for (int j = 0; j < 4; ++j) {
                    const f32x4 p = scratch[wpos * 512 + (di * 4 + j) * 64 + lane];
                    acc[2 * q + di][j].x += p.x; acc[2 * q + di][j].y += p.y;
                    acc[2 * q + di][j].z += p.z; acc[2 * q + di][j].w += p.w;
                }
        }
        __syncthreads();
    }

    // ---------------- epilogue: C/D layout col=lane&15, row=(lane>>4)*4+reg ------
    if (kg == 0) {
        const int orow = m0 + wm * 64 + lo * 4;
        const int ocol = n0 + wn * 64 + lr;
        #pragma unroll
        for (int i = 0; i < 4; ++i)
            #pragma unroll
            for (int j = 0; j < 4; ++j) {
                #pragma unroll
                for (int r = 0; r < 4; ++r)
                    out[(size_t)(orow + i * 16 + r) * OUT_F + ocol + j * 16] = acc[i][j][r];
            }
    }
}

extern "C" void kernel_launch(void* const* d_in, const int* in_sizes, int n_in,
                              void* d_out, int out_size, void* d_ws, size_t ws_size,
                              hipStream_t stream) {
    const float*    xp  = (const float*)d_in[0];
    const uint32_t* qw  = (const uint32_t*)d_in[1];
    const uint32_t* qz  = (const uint32_t*)d_in[2];
    const int*      qs  = (const int*)d_in[3];
    const float*    qsz = (const float*)d_in[4];
    const float*    qss = (const float*)d_in[5];
    // d_in[6] = g_idx: identity grouping (k/128), folded into the kernel.
    float* outp = (float*)d_out;

    const int grid = (TOKENS / BM) * (OUT_F / BN);   // 16 * 86 = 1376
    const size_t need = (size_t)TOKENS * IN_F * sizeof(f16);   // 16 MiB

    if (ws_size >= need) {
        f16* xws = (f16*)d_ws;
        cvt_perm_kernel<<<(TOKENS * IN_F / 8) / 256, 256, 0, stream>>>(xp, xws);
        qgemm_kernel<true><<<grid, 512, 0, stream>>>(xp, xws, qw, qz, qs, qsz, qss, outp);
    } else {
        qgemm_kernel<false><<<grid, 512, 0, stream>>>(xp, (const f16*)nullptr,
                                                      qw, qz, qs, qsz, qss, outp);
    }
}